// Round 1
// baseline (799.180 us; speedup 1.0000x reference)
//
#include <hip/hip_runtime.h>
#include <stdint.h>

// Softmax-Viterbi forward, 1024x1024, S=4.
// R8 pipeline (unchanged): 16 strip-blocks, per block:
//   wave0: chain (exp-domain cells, pure VALU+LDS)
//   wave1-4: producers (global float4 loads + exp2 -> P ring)
//   wave5: out-comms (LDS -> coherent global records + flag)
//   wave6: in-comms  (poll flag, coherent global -> LDS)
// R9: +240 HEATER blocks (bid 16..255). Evidence: VALUBusy=1.1% at an assumed
// 2.4 GHz implies ~19M SIMD-busy-cycles vs ~4-5M estimated from instruction
// counts, and the latency model predicts ~200us vs 700us measured -- both
// consistent with GFXCLK parked near ~600 MHz because the 16-block, mostly
// s_sleeping kernel looks idle to DPM. Heaters run register-only FMA spin
// (1 block/CU on the 240 unused CUs, zero memory/LDS interference) until
// strip 15 posts a done flag after writing out[0], keeping the governor at
// boost clocks. Pipeline math/flags byte-identical to R8.

#define MM    1024
#define LOG2E 1.4426950408889634f
#define LN2f  0.6931471805599453f
#define NEGI  (-1073741824)
#define CH    8
#define NCH   136
#define HCT   (NCH*2)                // half-chunks, 4 steps each

#define F_RIN   0
#define F_CDONE 1
#define F_OPUB  2
#define F_PD    4                    // F_PD + p (p=0..3): producer p done hc

#define DONE_FLAG  500               // prog[500]: strip15 region, unused slot
#define DONE_MAGIC 0x0051BEEF        // 0xAA poison is negative -> never matches

__device__ __forceinline__ float ld_cohf(const float* p) {
    return __hip_atomic_load(p, __ATOMIC_RELAXED, __HIP_MEMORY_SCOPE_AGENT);
}
__device__ __forceinline__ int ld_cohi(const int* p) {
    return __hip_atomic_load(p, __ATOMIC_RELAXED, __HIP_MEMORY_SCOPE_AGENT);
}
__device__ __forceinline__ void st_cohf(float* p, float v) {
    __hip_atomic_store(p, v, __ATOMIC_RELAXED, __HIP_MEMORY_SCOPE_AGENT);
}
__device__ __forceinline__ void st_cohi(int* p, int v) {
    __hip_atomic_store(p, v, __ATOMIC_RELAXED, __HIP_MEMORY_SCOPE_AGENT);
}
__device__ __forceinline__ int lds_acq(const int* p) {
    return __hip_atomic_load(p, __ATOMIC_ACQUIRE, __HIP_MEMORY_SCOPE_WORKGROUP);
}
__device__ __forceinline__ void lds_rel(int* p, int v) {
    __hip_atomic_store(p, v, __ATOMIC_RELEASE, __HIP_MEMORY_SCOPE_WORKGROUP);
}

__global__ __launch_bounds__(448, 1) void viterbi_r9(
    const float* __restrict__ theta, const float* __restrict__ A,
    float* __restrict__ out, float* __restrict__ bnd, int* __restrict__ prog)
{
    __shared__ float4 ldsP[4][4][5][64];    // 80 KB: [hc&3][step][P0..P3,Pt][row]
    __shared__ float  recIn[32][8];
    __shared__ float  recOut[32][8];
    __shared__ int    flags[8];

    const int tid  = threadIdx.x;
    const int bid  = blockIdx.x;

    if (bid >= 16) {
        // ===================== heater blocks =====================
        // Register-only FMA spin to keep DPM at boost clocks. No LDS, no
        // syncthreads, no memory traffic except one flag line every ~1k cyc.
        const int* done = prog + DONE_FLAG;
        float a0 = (float)(tid + 1) * 1.0e-8f;
        float a1 = a0 * 1.1f + 1.0e-8f, a2 = a0 * 1.2f + 2.0e-8f;
        float a3 = a0 * 1.3f + 3.0e-8f, a4 = a0 * 1.4f + 4.0e-8f;
        float a5 = a0 * 1.5f + 5.0e-8f, a6 = a0 * 1.6f + 6.0e-8f;
        float a7 = a0 * 1.7f + 7.0e-8f;
        const float c1 = 1.0000001f, c2 = 1.0e-9f;
        for (int it = 0; it < (1 << 17); ++it) {   // cap ~ safety only
            if (ld_cohi(done) == DONE_MAGIC) break;
#pragma unroll
            for (int k = 0; k < 128; ++k) {        // 1024 independent FMAs/poll
                a0 = __builtin_fmaf(a0, c1, c2);
                a1 = __builtin_fmaf(a1, c1, c2);
                a2 = __builtin_fmaf(a2, c1, c2);
                a3 = __builtin_fmaf(a3, c1, c2);
                a4 = __builtin_fmaf(a4, c1, c2);
                a5 = __builtin_fmaf(a5, c1, c2);
                a6 = __builtin_fmaf(a6, c1, c2);
                a7 = __builtin_fmaf(a7, c1, c2);
            }
        }
        float s = ((a0 + a1) + (a2 + a3)) + ((a4 + a5) + (a6 + a7));
        if (s == 12345.6789f)                       // never true; defeats DCE
            ((volatile float*)prog)[DONE_FLAG + 1] = s;
        return;
    }

    const int wv   = tid >> 6;
    const int lane = tid & 63;
    const int strip = ((bid & 7) << 1) | (bid >> 3);   // adjacent strips same XCD
    const bool isCons = (strip > 0);
    const bool isProd = (strip < 15);

    float* Prec = bnd + (size_t)strip * MM * 8;
    const float* Crec = bnd + (size_t)(strip - 1) * MM * 8;
    int* myflag = prog + strip * 32;
    const int* upflag = prog + (strip - 1) * 32;

    if (tid < 8) flags[tid] = -1;
    __syncthreads();

    if (wv == 0) {
        // ===================== chain wave =====================
        const int r = lane;
        int   mL = NEGI, mU = NEGI, mD = NEGI;
        float ql0=0,ql1=0,ql2=0,ql3=0;
        float qu0=0,qu1=0,qu2=0,qu3=0;
        float qd0=0,qd1=0,qd2=0,qd3=0;
        if (strip == 0 && lane == 0) { mD = 0; qd0=qd1=qd2=qd3=1.f; }
        if (isCons) {
            while (ld_cohi(upflag) < 1) __builtin_amdgcn_s_sleep(1);
            asm volatile("" ::: "memory");
            qu0 = ld_cohf(Crec+0); qu1 = ld_cohf(Crec+1);
            qu2 = ld_cohf(Crec+2); qu3 = ld_cohf(Crec+3);
            mU  = ld_cohi((const int*)Crec + 4);
        }
        for (int cc = 0; cc < NCH; ++cc) {
            if (isCons) while (lds_acq(&flags[F_RIN]) < cc) __builtin_amdgcn_s_sleep(1);
            if (isProd) while (lds_acq(&flags[F_OPUB]) < cc - 3) __builtin_amdgcn_s_sleep(1);
            const int slotBase = (cc & 3) * 8;
#pragma unroll
            for (int half = 0; half < 2; ++half) {
                const int h   = 2*cc + half;
                const int buf = h & 3;
                while (lds_acq(&flags[F_PD + buf]) < h) __builtin_amdgcn_s_sleep(1);
#pragma unroll
                for (int u2 = 0; u2 < 4; ++u2) {
                    const int u   = half*4 + u2;
                    const int tau = cc*CH + u;
                    const int jq  = tau - r + 1;
                    float4 P0 = ldsP[buf][u2][0][lane];
                    float4 P1 = ldsP[buf][u2][1][lane];
                    float4 P2 = ldsP[buf][u2][2][lane];
                    float4 P3 = ldsP[buf][u2][3][lane];
                    float4 Pt = ldsP[buf][u2][4][lane];
                    int off = max(max(mD, mU), mL);
                    float sd = ldexpf(1.0f, mD - off);
                    float su = ldexpf(1.0f, mU - off);
                    float sl = ldexpf(1.0f, mL - off);
                    float dm  = fmaf(qd1,P0.y, qd0*P0.x) + fmaf(qd3,P0.w, qd2*P0.z);
                    float dx  = fmaf(qu1,P1.y, qu0*P1.x) + fmaf(qu3,P1.w, qu2*P1.z);
                    float dy  = fmaf(ql1,P2.y, ql0*P2.x) + fmaf(ql3,P2.w, ql2*P2.z);
                    float ds2 = fmaf(qd1,P3.y, qd0*P3.x) + fmaf(qd3,P3.w, qd2*P3.z);
                    float g0 = (dm *sd)*Pt.x;
                    float g1 = (dx *su)*Pt.y;
                    float g2 = (dy *sl)*Pt.z;
                    float g3 = (ds2*sd)*Pt.w;
                    float gmax = fmaxf(fmaxf(g0,g1), fmaxf(g2,g3));
                    int e = (int)(__float_as_uint(gmax) >> 23) - 126;
                    float qn0 = ldexpf(g0, 1-e), qn1 = ldexpf(g1, 1-e);
                    float qn2 = ldexpf(g2, 1-e), qn3 = ldexpf(g3, 1-e);
                    int   mn  = off + e - 1;
                    const bool valid = (jq >= 1) && (jq <= MM);
                    if (!valid) { qn0=qn1=qn2=qn3=0.f; mn=NEGI; }
                    if (lane == 63) {
                        if (isProd) {
                            *(float4*)&recOut[slotBase + u][0] = make_float4(qn0,qn1,qn2,qn3);
                            recOut[slotBase + u][4] = __int_as_float(mn);
                        } else if (jq == MM) {
                            out[0] = LN2f * ((float)mn + log2f((qn0+qn1)+(qn2+qn3)));
                            st_cohi(prog + DONE_FLAG, DONE_MAGIC);   // release heaters
                        }
                    }
                    mD = mU; qd0=qu0; qd1=qu1; qd2=qu2; qd3=qu3;
                    int   mS = __shfl_up(mn, 1);
                    float s0 = __shfl_up(qn0,1), s1 = __shfl_up(qn1,1);
                    float s2 = __shfl_up(qn2,1), s3 = __shfl_up(qn3,1);
                    int bmv = NEGI; float b0=0,b1=0,b2=0,b3=0;
                    if (isCons) {
                        float4 bb = *(const float4*)&recIn[slotBase + u][0];
                        bmv = __float_as_int(recIn[slotBase + u][4]);
                        b0=bb.x; b1=bb.y; b2=bb.z; b3=bb.w;
                    }
                    if (lane == 0) { mS=bmv; s0=b0; s1=b1; s2=b2; s3=b3; }
                    mU = mS; qu0=s0; qu1=s1; qu2=s2; qu3=s3;
                    mL = mn; ql0=qn0; ql1=qn1; ql2=qn2; ql3=qn3;
                }
                if (lane == 0) lds_rel(&flags[F_CDONE], h);
            }
        }
    } else if (wv <= 4) {
        // ===================== producer waves (p = wv-1) =====================
        const int p = wv - 1;
        const int row = strip*64 + lane;
        const float4* A4 = (const float4*)A;
        const float4* T4 = (const float4*)theta;
        for (int h = p; h < HCT; h += 4) {
            // ring safety: slot h&3 free once chain consumed h-4
            while (lds_acq(&flags[F_CDONE]) < h - 4) __builtin_amdgcn_s_sleep(1);
            float4 a[4][4]; float4 th[4];
#pragma unroll
            for (int u2 = 0; u2 < 4; ++u2) {
                int tau = 4*h + u2;
                int c = tau - lane; c = c < 0 ? 0 : (c > MM-1 ? MM-1 : c);
                const float4* Ar = A4 + ((size_t)row*MM + (size_t)c)*4;
                a[u2][0] = Ar[0]; a[u2][1] = Ar[1]; a[u2][2] = Ar[2]; a[u2][3] = Ar[3];
                th[u2]   = T4[(size_t)row*MM + (size_t)c];
            }
            const int buf = h & 3;
#pragma unroll
            for (int u2 = 0; u2 < 4; ++u2) {
                float4 p0, p1, p2, p3, pt;
                p0.x=exp2f(a[u2][0].x*LOG2E); p0.y=exp2f(a[u2][0].y*LOG2E);
                p0.z=exp2f(a[u2][0].z*LOG2E); p0.w=exp2f(a[u2][0].w*LOG2E);
                p1.x=exp2f(a[u2][1].x*LOG2E); p1.y=exp2f(a[u2][1].y*LOG2E);
                p1.z=exp2f(a[u2][1].z*LOG2E); p1.w=exp2f(a[u2][1].w*LOG2E);
                p2.x=exp2f(a[u2][2].x*LOG2E); p2.y=exp2f(a[u2][2].y*LOG2E);
                p2.z=exp2f(a[u2][2].z*LOG2E); p2.w=exp2f(a[u2][2].w*LOG2E);
                p3.x=exp2f(a[u2][3].x*LOG2E); p3.y=exp2f(a[u2][3].y*LOG2E);
                p3.z=exp2f(a[u2][3].z*LOG2E); p3.w=exp2f(a[u2][3].w*LOG2E);
                pt.x=exp2f(th[u2].x*LOG2E);   pt.y=exp2f(th[u2].y*LOG2E);
                pt.z=exp2f(th[u2].z*LOG2E);   pt.w=exp2f(th[u2].w*LOG2E);
                ldsP[buf][u2][0][lane]=p0; ldsP[buf][u2][1][lane]=p1;
                ldsP[buf][u2][2][lane]=p2; ldsP[buf][u2][3][lane]=p3;
                ldsP[buf][u2][4][lane]=pt;
            }
            if (lane == 0) lds_rel(&flags[F_PD + p], h);
        }
    } else if (wv == 5) {
        // ===================== out-comms wave =====================
        if (!isProd) return;
        const int rec0 = lane / 5, wd0 = lane % 5;
        const int rec1 = (lane+64) / 5, wd1 = (lane+64) % 5;
        const bool on1 = (lane + 64) < 80;
        for (int cc = 0; cc < NCH; cc += 2) {
            while (lds_acq(&flags[F_CDONE]) < 2*cc + 3) __builtin_amdgcn_s_sleep(1);
            {
                int col = 8*(cc + (rec0 >> 3)) + (rec0 & 7) - 62;
                float v = recOut[(cc & 3)*8 + rec0][wd0];
                if (col >= 1 && col <= MM) st_cohf(Prec + (size_t)(col-1)*8 + wd0, v);
            }
            if (on1) {
                int col = 8*(cc + (rec1 >> 3)) + (rec1 & 7) - 62;
                float v = recOut[(cc & 3)*8 + rec1][wd1];
                if (col >= 1 && col <= MM) st_cohf(Prec + (size_t)(col-1)*8 + wd1, v);
            }
            asm volatile("s_waitcnt vmcnt(0)" ::: "memory");
            int done = 8*(cc + 1) - 55; if (done > MM) done = MM;
            if (done >= 1 && lane == 0) st_cohi(myflag, done);
            if (lane == 0) lds_rel(&flags[F_OPUB], cc + 1);
        }
    } else {
        // ===================== in-comms wave =====================
        if (!isCons) return;
        const int rec0 = lane / 5, wd0 = lane % 5;
        const int rec1 = (lane+64) / 5, wd1 = (lane+64) % 5;
        const bool on1 = (lane + 64) < 80;
        for (int cc = 0; cc < NCH; cc += 2) {
            while (lds_acq(&flags[F_CDONE]) < 2*cc - 3) __builtin_amdgcn_s_sleep(1);
            int need = 8*cc + 17; if (need > MM) need = MM;
            while (ld_cohi(upflag) < need) __builtin_amdgcn_s_sleep(1);
            asm volatile("" ::: "memory");
            {
                int col = 8*cc + 2 + rec0; if (col > MM) col = MM;
                float v = ld_cohf(Crec + (size_t)(col-1)*8 + wd0);
                recIn[(cc & 3)*8 + rec0][wd0] = v;
            }
            if (on1) {
                int col = 8*cc + 2 + rec1; if (col > MM) col = MM;
                float v = ld_cohf(Crec + (size_t)(col-1)*8 + wd1);
                recIn[(cc & 3)*8 + rec1][wd1] = v;
            }
            if (lane == 0) lds_rel(&flags[F_RIN], cc + 1);
        }
    }
}

extern "C" void kernel_launch(void* const* d_in, const int* in_sizes, int n_in,
                              void* d_out, int out_size, void* d_ws, size_t ws_size,
                              hipStream_t stream) {
    const float* theta = (const float*)d_in[0];   // [1024,1024,4] f32
    const float* A     = (const float*)d_in[1];   // [1024,1024,4,4] f32
    float* out = (float*)d_out;                   // [1] f32
    // ws: records [16][1024][8] f32 (512 KB), then flags [16*32] int.
    // 0xAA poison -> flags negative -> consumers spin until first real post;
    // prog[500] doubles as the heater-release flag (poison != DONE_MAGIC).
    float* bnd = (float*)d_ws;
    int*  prog = (int*)((char*)d_ws + (size_t)16 * MM * 8 * sizeof(float));
    // 16 real strip blocks + 240 heater blocks (1 block/CU at 84 KB LDS).
    viterbi_r9<<<256, 448, 0, stream>>>(theta, A, out, bnd, prog);
}

// Round 2
// 710.904 us; speedup vs baseline: 1.1242x; 1.1242x over previous
//
#include <hip/hip_runtime.h>
#include <stdint.h>

// Softmax-Viterbi forward, 1024x1024, S=4.
// R10: attack exposed latency on the wavefront critical path (~790 cy/step).
//  - Chain: replace 5x __shfl_up(x,1) (ds_bpermute, ~120cy exposed/step) with
//    DPP WAVE_SHR1 (VALU-latency lane shift). DPP's "old" operand doubles as
//    the lane-0 boundary injection -> the if(lane==0) select disappears.
//  - Producers: 8 waves (was 4) + ring depth 8 -> per-half-chunk producer
//    serial latency (diverged 64-line gathers + HBM wait + exp2) amortized 8x.
//  - Fold theta into exp: p = exp2((a+theta)*log2e). exp2 96->64 per hc,
//    drops the Pt LDS plane (ring slot 20KB->16KB so ring-8 = 128KB fits),
//    removes one multiply from the chain's dependent path.
//  - Chain spins sleepless (latency-critical agent); s_setprio(1) on chain.
//  - Heaters removed (R9 falsified the parked-clock theory: VALUBusy 88%,
//    duration unchanged/worse).
// Waves per block (704 thr): 0=chain, 1-8=producers, 9=out-comms, 10=in-comms.

#define MM    1024
#define LOG2E 1.4426950408889634f
#define LN2f  0.6931471805599453f
#define NEGI  (-1073741824)
#define CH    8
#define NCH   136
#define HCT   (NCH*2)                // half-chunks, 4 steps each

#define F_RIN   0
#define F_CDONE 1
#define F_OPUB  2
#define F_PD    4                    // F_PD + p (p=0..7): producer p done hc

__device__ __forceinline__ float ld_cohf(const float* p) {
    return __hip_atomic_load(p, __ATOMIC_RELAXED, __HIP_MEMORY_SCOPE_AGENT);
}
__device__ __forceinline__ int ld_cohi(const int* p) {
    return __hip_atomic_load(p, __ATOMIC_RELAXED, __HIP_MEMORY_SCOPE_AGENT);
}
__device__ __forceinline__ void st_cohf(float* p, float v) {
    __hip_atomic_store(p, v, __ATOMIC_RELAXED, __HIP_MEMORY_SCOPE_AGENT);
}
__device__ __forceinline__ void st_cohi(int* p, int v) {
    __hip_atomic_store(p, v, __ATOMIC_RELAXED, __HIP_MEMORY_SCOPE_AGENT);
}
__device__ __forceinline__ int lds_acq(const int* p) {
    return __hip_atomic_load(p, __ATOMIC_ACQUIRE, __HIP_MEMORY_SCOPE_WORKGROUP);
}
__device__ __forceinline__ void lds_rel(int* p, int v) {
    __hip_atomic_store(p, v, __ATOMIC_RELEASE, __HIP_MEMORY_SCOPE_WORKGROUP);
}

// DPP wave_shr1: lane n <- lane n-1; lane 0 <- oldv (bound_ctrl=false keeps old).
// dpp_ctrl 0x138 = WAVE_SHR1 (gfx9/CDNA lineage; removed only in gfx10+).
__device__ __forceinline__ int dpp_shr1_i(int oldv, int src) {
    return __builtin_amdgcn_update_dpp(oldv, src, 0x138, 0xF, 0xF, false);
}
__device__ __forceinline__ float dpp_shr1_f(float oldv, float src) {
    return __int_as_float(__builtin_amdgcn_update_dpp(
        __float_as_int(oldv), __float_as_int(src), 0x138, 0xF, 0xF, false));
}

__global__ __launch_bounds__(704, 1) void viterbi_r10(
    const float* __restrict__ theta, const float* __restrict__ A,
    float* __restrict__ out, float* __restrict__ bnd, int* __restrict__ prog)
{
    __shared__ float4 ldsP[8][4][4][64];    // 128 KB: [hc&7][step][P0..P3][row]
    __shared__ float  recIn[32][8];
    __shared__ float  recOut[32][8];
    __shared__ int    flags[16];

    const int tid  = threadIdx.x;
    const int wv   = tid >> 6;
    const int lane = tid & 63;
    const int bid  = blockIdx.x;
    const int strip = ((bid & 7) << 1) | (bid >> 3);   // adjacent strips same XCD
    const bool isCons = (strip > 0);
    const bool isProd = (strip < 15);

    float* Prec = bnd + (size_t)strip * MM * 8;
    const float* Crec = bnd + (size_t)(strip - 1) * MM * 8;
    int* myflag = prog + strip * 32;
    const int* upflag = prog + (strip - 1) * 32;

    if (tid < 16) flags[tid] = -1;
    __syncthreads();

    if (wv == 0) {
        // ===================== chain wave =====================
        __builtin_amdgcn_s_setprio(1);      // critical-path wave; shares SIMD0
        const int r = lane;
        int   mL = NEGI, mU = NEGI, mD = NEGI;
        float ql0=0,ql1=0,ql2=0,ql3=0;
        float qu0=0,qu1=0,qu2=0,qu3=0;
        float qd0=0,qd1=0,qd2=0,qd3=0;
        if (strip == 0 && lane == 0) { mD = 0; qd0=qd1=qd2=qd3=1.f; }
        if (isCons) {
            while (ld_cohi(upflag) < 1) __builtin_amdgcn_s_sleep(1);
            asm volatile("" ::: "memory");
            qu0 = ld_cohf(Crec+0); qu1 = ld_cohf(Crec+1);
            qu2 = ld_cohf(Crec+2); qu3 = ld_cohf(Crec+3);
            mU  = ld_cohi((const int*)Crec + 4);
        }
        for (int cc = 0; cc < NCH; ++cc) {
            if (isCons) while (lds_acq(&flags[F_RIN]) < cc) {}
            if (isProd) while (lds_acq(&flags[F_OPUB]) < cc - 3) {}
            const int slotBase = (cc & 3) * 8;
#pragma unroll
            for (int half = 0; half < 2; ++half) {
                const int h   = 2*cc + half;
                const int buf = h & 7;
                while (lds_acq(&flags[F_PD + buf]) < h) {}
#pragma unroll
                for (int u2 = 0; u2 < 4; ++u2) {
                    const int u   = half*4 + u2;
                    const int tau = cc*CH + u;
                    const int jq  = tau - r + 1;
                    float4 P0 = ldsP[buf][u2][0][lane];
                    float4 P1 = ldsP[buf][u2][1][lane];
                    float4 P2 = ldsP[buf][u2][2][lane];
                    float4 P3 = ldsP[buf][u2][3][lane];
                    int off = max(max(mD, mU), mL);
                    float sd = ldexpf(1.0f, mD - off);
                    float su = ldexpf(1.0f, mU - off);
                    float sl = ldexpf(1.0f, mL - off);
                    float dm  = fmaf(qd1,P0.y, qd0*P0.x) + fmaf(qd3,P0.w, qd2*P0.z);
                    float dx  = fmaf(qu1,P1.y, qu0*P1.x) + fmaf(qu3,P1.w, qu2*P1.z);
                    float dy  = fmaf(ql1,P2.y, ql0*P2.x) + fmaf(ql3,P2.w, ql2*P2.z);
                    float ds2 = fmaf(qd1,P3.y, qd0*P3.x) + fmaf(qd3,P3.w, qd2*P3.z);
                    float g0 = dm *sd;                // theta folded into P by producer
                    float g1 = dx *su;
                    float g2 = dy *sl;
                    float g3 = ds2*sd;
                    float gmax = fmaxf(fmaxf(g0,g1), fmaxf(g2,g3));
                    int e = (int)(__float_as_uint(gmax) >> 23) - 126;
                    float qn0 = ldexpf(g0, 1-e), qn1 = ldexpf(g1, 1-e);
                    float qn2 = ldexpf(g2, 1-e), qn3 = ldexpf(g3, 1-e);
                    int   mn  = off + e - 1;
                    const bool valid = (jq >= 1) && (jq <= MM);
                    if (!valid) { qn0=qn1=qn2=qn3=0.f; mn=NEGI; }
                    if (lane == 63) {
                        if (isProd) {
                            *(float4*)&recOut[slotBase + u][0] = make_float4(qn0,qn1,qn2,qn3);
                            recOut[slotBase + u][4] = __int_as_float(mn);
                        } else if (jq == MM) {
                            out[0] = LN2f * ((float)mn + log2f((qn0+qn1)+(qn2+qn3)));
                        }
                    }
                    // boundary values for lane 0 (DPP "old" operand)
                    int bmv = NEGI; float b0=0,b1=0,b2=0,b3=0;
                    if (isCons) {
                        float4 bb = *(const float4*)&recIn[slotBase + u][0];
                        bmv = __float_as_int(recIn[slotBase + u][4]);
                        b0=bb.x; b1=bb.y; b2=bb.z; b3=bb.w;
                    }
                    mD = mU; qd0=qu0; qd1=qu1; qd2=qu2; qd3=qu3;
                    mU  = dpp_shr1_i(bmv, mn);
                    qu0 = dpp_shr1_f(b0, qn0);
                    qu1 = dpp_shr1_f(b1, qn1);
                    qu2 = dpp_shr1_f(b2, qn2);
                    qu3 = dpp_shr1_f(b3, qn3);
                    mL = mn; ql0=qn0; ql1=qn1; ql2=qn2; ql3=qn3;
                }
                if (lane == 0) lds_rel(&flags[F_CDONE], h);
            }
        }
    } else if (wv <= 8) {
        // ===================== producer waves (p = wv-1, 8 of them) ==========
        const int p = wv - 1;
        const int row = strip*64 + lane;
        const float4* A4 = (const float4*)A;
        const float4* T4 = (const float4*)theta;
        for (int h = p; h < HCT; h += 8) {
            // ring safety: slot h&7 (owned solely by producer p) free once
            // chain consumed h-8
            while (lds_acq(&flags[F_CDONE]) < h - 8) __builtin_amdgcn_s_sleep(1);
            float4 a[4][4]; float4 th[4];
#pragma unroll
            for (int u2 = 0; u2 < 4; ++u2) {
                int tau = 4*h + u2;
                int c = tau - lane; c = c < 0 ? 0 : (c > MM-1 ? MM-1 : c);
                const float4* Ar = A4 + ((size_t)row*MM + (size_t)c)*4;
                a[u2][0] = Ar[0]; a[u2][1] = Ar[1]; a[u2][2] = Ar[2]; a[u2][3] = Ar[3];
                th[u2]   = T4[(size_t)row*MM + (size_t)c];
            }
            const int buf = h & 7;
#pragma unroll
            for (int u2 = 0; u2 < 4; ++u2) {
                float4 p0, p1, p2, p3;
                // theta folded: P_row_s = exp2((A_row_s + theta_s) * log2e)
                p0.x=exp2f((a[u2][0].x+th[u2].x)*LOG2E);
                p0.y=exp2f((a[u2][0].y+th[u2].x)*LOG2E);
                p0.z=exp2f((a[u2][0].z+th[u2].x)*LOG2E);
                p0.w=exp2f((a[u2][0].w+th[u2].x)*LOG2E);
                p1.x=exp2f((a[u2][1].x+th[u2].y)*LOG2E);
                p1.y=exp2f((a[u2][1].y+th[u2].y)*LOG2E);
                p1.z=exp2f((a[u2][1].z+th[u2].y)*LOG2E);
                p1.w=exp2f((a[u2][1].w+th[u2].y)*LOG2E);
                p2.x=exp2f((a[u2][2].x+th[u2].z)*LOG2E);
                p2.y=exp2f((a[u2][2].y+th[u2].z)*LOG2E);
                p2.z=exp2f((a[u2][2].z+th[u2].z)*LOG2E);
                p2.w=exp2f((a[u2][2].w+th[u2].z)*LOG2E);
                p3.x=exp2f((a[u2][3].x+th[u2].w)*LOG2E);
                p3.y=exp2f((a[u2][3].y+th[u2].w)*LOG2E);
                p3.z=exp2f((a[u2][3].z+th[u2].w)*LOG2E);
                p3.w=exp2f((a[u2][3].w+th[u2].w)*LOG2E);
                ldsP[buf][u2][0][lane]=p0; ldsP[buf][u2][1][lane]=p1;
                ldsP[buf][u2][2][lane]=p2; ldsP[buf][u2][3][lane]=p3;
            }
            if (lane == 0) lds_rel(&flags[F_PD + p], h);
        }
    } else if (wv == 9) {
        // ===================== out-comms wave =====================
        if (!isProd) return;
        const int rec0 = lane / 5, wd0 = lane % 5;
        const int rec1 = (lane+64) / 5, wd1 = (lane+64) % 5;
        const bool on1 = (lane + 64) < 80;
        for (int cc = 0; cc < NCH; cc += 2) {
            while (lds_acq(&flags[F_CDONE]) < 2*cc + 3) __builtin_amdgcn_s_sleep(1);
            {
                int col = 8*(cc + (rec0 >> 3)) + (rec0 & 7) - 62;
                float v = recOut[(cc & 3)*8 + rec0][wd0];
                if (col >= 1 && col <= MM) st_cohf(Prec + (size_t)(col-1)*8 + wd0, v);
            }
            if (on1) {
                int col = 8*(cc + (rec1 >> 3)) + (rec1 & 7) - 62;
                float v = recOut[(cc & 3)*8 + rec1][wd1];
                if (col >= 1 && col <= MM) st_cohf(Prec + (size_t)(col-1)*8 + wd1, v);
            }
            asm volatile("s_waitcnt vmcnt(0)" ::: "memory");
            int done = 8*(cc + 1) - 55; if (done > MM) done = MM;
            if (done >= 1 && lane == 0) st_cohi(myflag, done);
            if (lane == 0) lds_rel(&flags[F_OPUB], cc + 1);
        }
    } else {
        // ===================== in-comms wave =====================
        if (!isCons) return;
        const int rec0 = lane / 5, wd0 = lane % 5;
        const int rec1 = (lane+64) / 5, wd1 = (lane+64) % 5;
        const bool on1 = (lane + 64) < 80;
        for (int cc = 0; cc < NCH; cc += 2) {
            while (lds_acq(&flags[F_CDONE]) < 2*cc - 3) __builtin_amdgcn_s_sleep(1);
            int need = 8*cc + 17; if (need > MM) need = MM;
            while (ld_cohi(upflag) < need) __builtin_amdgcn_s_sleep(1);
            asm volatile("" ::: "memory");
            {
                int col = 8*cc + 2 + rec0; if (col > MM) col = MM;
                float v = ld_cohf(Crec + (size_t)(col-1)*8 + wd0);
                recIn[(cc & 3)*8 + rec0][wd0] = v;
            }
            if (on1) {
                int col = 8*cc + 2 + rec1; if (col > MM) col = MM;
                float v = ld_cohf(Crec + (size_t)(col-1)*8 + wd1);
                recIn[(cc & 3)*8 + rec1][wd1] = v;
            }
            if (lane == 0) lds_rel(&flags[F_RIN], cc + 1);
        }
    }
}

extern "C" void kernel_launch(void* const* d_in, const int* in_sizes, int n_in,
                              void* d_out, int out_size, void* d_ws, size_t ws_size,
                              hipStream_t stream) {
    const float* theta = (const float*)d_in[0];   // [1024,1024,4] f32
    const float* A     = (const float*)d_in[1];   // [1024,1024,4,4] f32
    float* out = (float*)d_out;                   // [1] f32
    // ws: records [16][1024][8] f32 (512 KB), then flags [16*32] int.
    // 0xAA poison -> flags negative -> consumers spin until first real post.
    float* bnd = (float*)d_ws;
    int*  prog = (int*)((char*)d_ws + (size_t)16 * MM * 8 * sizeof(float));
    viterbi_r10<<<16, 704, 0, stream>>>(theta, A, out, bnd, prog);
}